// Round 1
// baseline (509.160 us; speedup 1.0000x reference)
//
#include <hip/hip_runtime.h>
#include <hip/hip_bf16.h>

#define ROI 5
#define NPTS 25          // 5*5
#define CCH 256
#define HH 135
#define WW 240
#define HWP (HH * WW)    // 32400
#define NB 8
#define NN 1024

// ---------------------------------------------------------------------------
// Pass 1: transpose [B, C, H*W] -> [B, H*W, C] via 32x32 LDS tiles
// ---------------------------------------------------------------------------
__global__ __launch_bounds__(256) void transpose_kernel(const float* __restrict__ fm,
                                                        float* __restrict__ fmT) {
    __shared__ float tile[32][33];   // +1 pad breaks bank conflicts
    int b   = blockIdx.z;
    int hw0 = blockIdx.x * 32;
    int c0  = blockIdx.y * 32;
    int tx  = threadIdx.x;           // 0..31 (fast dim)
    int ty  = threadIdx.y;           // 0..7

    const float* src = fm + (size_t)b * CCH * HWP;
#pragma unroll
    for (int j = 0; j < 32; j += 8) {
        int hw = hw0 + tx;
        int c  = c0 + ty + j;
        if (hw < HWP) tile[ty + j][tx] = src[(size_t)c * HWP + hw];
    }
    __syncthreads();
    float* dst = fmT + (size_t)b * HWP * CCH;
#pragma unroll
    for (int j = 0; j < 32; j += 8) {
        int hw = hw0 + ty + j;
        int c  = c0 + tx;
        if (hw < HWP) dst[(size_t)hw * CCH + c] = tile[tx][ty + j];
    }
}

// ---------------------------------------------------------------------------
// Pass 2: one block per ROI (8192 blocks x 256 threads).
// TRANSPOSED=true : read fmT[b][hw][c] (channel-contiguous, coalesced)
// TRANSPOSED=false: read fm [b][c][hw] (fallback when ws too small)
// ---------------------------------------------------------------------------
template <bool TRANSPOSED>
__global__ __launch_bounds__(256) void roi_kernel(const float* __restrict__ fmsrc,
                                                  const float* __restrict__ cand,
                                                  float* __restrict__ out) {
    // result tile in OUTPUT layout [c*25 + p]; written conflict-free, flushed coalesced
    __shared__ __align__(16) float res[CCH * NPTS];   // 25600 B
    __shared__ int   s_y0[NPTS], s_x0[NPTS], s_y1[NPTS], s_x1[NPTS];
    __shared__ float s_w[4][NPTS];

    int blk = blockIdx.x;          // 0..8191
    int b   = blk >> 10;
    int n   = blk & 1023;
    int t   = threadIdx.x;

    float cx = cand[(b * NN + n) * 2 + 0];
    float cy = cand[(b * NN + n) * 2 + 1];

    if (t < NPTS) {
        int py = t / ROI, px = t % ROI;
        // off = (i + 0.5) * (BOX/ROI_SIZE) computed in fp32, matching jnp
        float y = (cy - 2.0f) + ((float)py + 0.5f) * 0.8f;
        float x = (cx - 2.0f) + ((float)px + 0.5f) * 0.8f;
        bool valid = (y > -1.0f) && (y < (float)HH) && (x > -1.0f) && (x < (float)WW);
        y = fmaxf(y, 0.0f);
        x = fmaxf(x, 0.0f);
        int y0 = (int)floorf(y);
        int x0 = (int)floorf(x);
        bool yc = (y0 >= HH - 1);
        bool xc = (x0 >= WW - 1);
        if (yc) y0 = HH - 1;
        if (xc) x0 = WW - 1;
        int y1 = min(y0 + 1, HH - 1);
        int x1 = min(x0 + 1, WW - 1);
        float ly = yc ? 0.0f : y - (float)y0;
        float lx = xc ? 0.0f : x - (float)x0;
        float hy = 1.0f - ly, hx = 1.0f - lx;
        float v  = valid ? 1.0f : 0.0f;   // fold valid-mask into the weights
        s_y0[t] = y0; s_x0[t] = x0; s_y1[t] = y1; s_x1[t] = x1;
        s_w[0][t] = hy * hx * v;
        s_w[1][t] = hy * lx * v;
        s_w[2][t] = ly * hx * v;
        s_w[3][t] = ly * lx * v;
    }
    __syncthreads();

    int sub  = t >> 6;     // wave id 0..3 -> handles points p = sub, sub+4, ...
    int lane = t & 63;

    for (int p = sub; p < NPTS; p += 4) {
        int y0 = s_y0[p], x0 = s_x0[p], y1 = s_y1[p], x1 = s_x1[p];
        float w00 = s_w[0][p], w01 = s_w[1][p], w10 = s_w[2][p], w11 = s_w[3][p];

        const float *p00, *p01, *p10, *p11;
        size_t cstride;
        if (TRANSPOSED) {
            const float* base = fmsrc + (size_t)b * HWP * CCH;
            p00 = base + (size_t)(y0 * WW + x0) * CCH;
            p01 = base + (size_t)(y0 * WW + x1) * CCH;
            p10 = base + (size_t)(y1 * WW + x0) * CCH;
            p11 = base + (size_t)(y1 * WW + x1) * CCH;
            cstride = 1;
        } else {
            const float* base = fmsrc + (size_t)b * CCH * HWP;
            p00 = base + (y0 * WW + x0);
            p01 = base + (y0 * WW + x1);
            p10 = base + (y1 * WW + x0);
            p11 = base + (y1 * WW + x1);
            cstride = HWP;
        }
#pragma unroll
        for (int i = 0; i < 4; i++) {
            int c = lane + 64 * i;   // lane-stride 1 in channel -> coalesced reads
            size_t co = (size_t)c * cstride;
            float v00 = p00[co], v01 = p01[co], v10 = p10[co], v11 = p11[co];
            // lds index stride per lane = 25 floats (odd) -> 2 lanes/bank, free
            res[c * NPTS + p] = w00 * v00 + w01 * v01 + w10 * v10 + w11 * v11;
        }
    }
    __syncthreads();

    // Coalesced flush: 6400 floats = 1600 float4
    float4* o4 = (float4*)(out + (size_t)blk * (CCH * NPTS));
    const float4* r4 = (const float4*)res;
    for (int k = t; k < (CCH * NPTS) / 4; k += 256) {
        o4[k] = r4[k];
    }
}

extern "C" void kernel_launch(void* const* d_in, const int* in_sizes, int n_in,
                              void* d_out, int out_size, void* d_ws, size_t ws_size,
                              hipStream_t stream) {
    const float* fm   = (const float*)d_in[0];
    const float* cand = (const float*)d_in[1];
    float* out        = (float*)d_out;

    size_t needed = (size_t)NB * HWP * CCH * sizeof(float);  // 265.4 MB
    if (ws_size >= needed) {
        float* fmT = (float*)d_ws;
        dim3 tb(32, 8);
        dim3 tg((HWP + 31) / 32, CCH / 32, NB);
        transpose_kernel<<<tg, tb, 0, stream>>>(fm, fmT);
        roi_kernel<true><<<NB * NN, 256, 0, stream>>>(fmT, cand, out);
    } else {
        roi_kernel<false><<<NB * NN, 256, 0, stream>>>(fm, cand, out);
    }
}

// Round 2
// 491.099 us; speedup vs baseline: 1.0368x; 1.0368x over previous
//
#include <hip/hip_runtime.h>
#include <hip/hip_fp16.h>

#define ROI 5
#define NPTS 25          // 5*5
#define CCH 256
#define HH 135
#define WW 240
#define HWP (HH * WW)    // 32400
#define NV4 (HWP / 4)    // 8100 float4 per plane
#define NB 8
#define NN 1024

// One block per (b, c). Load the 135x240 fp32 plane coalesced, store as fp16
// in LDS (64,800 B -- fits the 64 KiB block limit), then evaluate all
// 1024 ROIs x 25 points for this channel from LDS.
//  - global reads: each plane read exactly once, float4-coalesced (265 MB total)
//  - global writes: contiguous 25-float runs per (n,c) (~78% line efficiency)
//  - no transpose pass, no workspace needed
__global__ __launch_bounds__(1024) void roi_plane_kernel(const float* __restrict__ fm,
                                                         const float* __restrict__ cand,
                                                         float* __restrict__ out) {
    __shared__ __half plane[HWP];   // 64,800 bytes

    int blk = blockIdx.x;           // 0..2047
    int c   = blk & (CCH - 1);
    int b   = blk >> 8;
    int t   = threadIdx.x;          // 0..1023

    // ---- stage plane (b,c) into LDS as fp16 ----
    const float4* src = (const float4*)(fm + ((size_t)b * CCH + c) * HWP);
#pragma unroll
    for (int j = 0; j < 8; j++) {
        int e = j * 1024 + t;
        if (e < NV4) {
            float4 v = src[e];
            __half2* d = (__half2*)(plane + e * 4);   // 8B-aligned
            d[0] = __half2(__float2half(v.x), __float2half(v.y));
            d[1] = __half2(__float2half(v.z), __float2half(v.w));
        }
    }
    __syncthreads();

    const float* cb = cand + (size_t)b * NN * 2;
    float* ob = out + (size_t)b * NN * (CCH * NPTS) + c * NPTS;

    // 1024*25 = 25600 (n,p) pairs; 25 iterations, p-fast ordering so that
    // consecutive lanes write consecutive output floats within a 25-run.
    for (int k = 0; k < NPTS; k++) {
        int idx = k * 1024 + t;      // < 25600 exactly
        int n   = idx / 25;
        int p   = idx - n * 25;
        int py  = p / 5;
        int px  = p - py * 5;

        float cx = cb[n * 2 + 0];
        float cy = cb[n * 2 + 1];

        // exact torchvision roi_align sampling math (fp32, matches reference)
        float y = (cy - 2.0f) + ((float)py + 0.5f) * 0.8f;
        float x = (cx - 2.0f) + ((float)px + 0.5f) * 0.8f;
        bool valid = (y > -1.0f) && (y < (float)HH) && (x > -1.0f) && (x < (float)WW);
        y = fmaxf(y, 0.0f);
        x = fmaxf(x, 0.0f);
        int y0 = (int)y;             // y >= 0, trunc == floor
        int x0 = (int)x;
        bool yc = (y0 >= HH - 1);
        bool xc = (x0 >= WW - 1);
        if (yc) y0 = HH - 1;
        if (xc) x0 = WW - 1;
        int y1 = min(y0 + 1, HH - 1);
        int x1 = min(x0 + 1, WW - 1);
        float ly = yc ? 0.0f : y - (float)y0;
        float lx = xc ? 0.0f : x - (float)x0;
        float hy = 1.0f - ly, hx = 1.0f - lx;
        float vm = valid ? 1.0f : 0.0f;

        int r0 = y0 * WW, r1 = y1 * WW;
        float v00 = __half2float(plane[r0 + x0]);
        float v01 = __half2float(plane[r0 + x1]);
        float v10 = __half2float(plane[r1 + x0]);
        float v11 = __half2float(plane[r1 + x1]);

        float r = (hy * hx * v00 + hy * lx * v01 + ly * hx * v10 + ly * lx * v11) * vm;
        ob[(size_t)n * (CCH * NPTS) + p] = r;
    }
}

extern "C" void kernel_launch(void* const* d_in, const int* in_sizes, int n_in,
                              void* d_out, int out_size, void* d_ws, size_t ws_size,
                              hipStream_t stream) {
    const float* fm   = (const float*)d_in[0];
    const float* cand = (const float*)d_in[1];
    float* out        = (float*)d_out;

    roi_plane_kernel<<<NB * CCH, 1024, 0, stream>>>(fm, cand, out);
}